// Round 5
// baseline (2031.365 us; speedup 1.0000x reference)
//
#include <hip/hip_runtime.h>
#include <cmath>
#include <cstdint>
#include <cstddef>

#define BB 256      // batch
#define MM 8192     // checks
#define NN 16384    // variables
#define DEG 10
#define MAX_ITER 30
#define PAR_BLOCKS 64

typedef unsigned char  u8;
typedef unsigned short u16;

// ---------------- prologue kernels ----------------

__global__ void k_init(int* colcnt, int* colfill, int* mm, int* niter, int* conv, int* cnt) {
    int t = blockIdx.x * blockDim.x + threadIdx.x;
    if (t < NN) { colcnt[t] = 0; colfill[t] = 0; }
    if (t < BB) { mm[t] = 0; niter[t] = -1; conv[t] = 0; }
    if (t == 0) *cnt = 0;
}

// transpose f32: in (R,C) row-major -> out (C,R); optional duplicate out2
__global__ void k_transpose_f32(const float* __restrict__ in, float* __restrict__ out,
                                float* __restrict__ out2, int R, int C) {
    __shared__ float tile[64][65];
    int c0 = blockIdx.x * 64;
    int r0 = blockIdx.y * 64;
    #pragma unroll
    for (int k = 0; k < 16; k++) {
        int idx = k * 256 + threadIdx.x;
        int i = idx >> 6, j = idx & 63;
        tile[i][j] = in[(size_t)(r0 + i) * C + (c0 + j)];
    }
    __syncthreads();
    #pragma unroll
    for (int k = 0; k < 16; k++) {
        int idx = k * 256 + threadIdx.x;
        int i = idx >> 6, j = idx & 63;
        float v = tile[j][i];
        size_t o = (size_t)(c0 + i) * R + (r0 + j);
        out[o] = v;
        if (out2) out2[o] = v;
    }
}

// synd (B,M) f32 -> syndb (M,B) byte
__global__ void k_synd_t(const float* __restrict__ synd, u8* __restrict__ syndb) {
    __shared__ float tile[64][65];
    int c0 = blockIdx.x * 64;   // m
    int r0 = blockIdx.y * 64;   // b
    #pragma unroll
    for (int k = 0; k < 16; k++) {
        int idx = k * 256 + threadIdx.x;
        int i = idx >> 6, j = idx & 63;
        tile[i][j] = synd[(size_t)(r0 + i) * MM + (c0 + j)];
    }
    __syncthreads();
    #pragma unroll
    for (int k = 0; k < 16; k++) {
        int idx = k * 256 + threadIdx.x;
        int i = idx >> 6, j = idx & 63;
        syndb[(size_t)(c0 + i) * BB + (r0 + j)] = (tile[j][i] != 0.0f) ? 1 : 0;
    }
}

__global__ void k_hist(const int* __restrict__ vc, int* colcnt) {
    int e = blockIdx.x * 256 + threadIdx.x;
    if (e >= MM * DEG) return;
    int c = vc[e];
    if (c < NN) atomicAdd(&colcnt[c], 1);
}

__global__ void k_scan(const int* __restrict__ colcnt, int* __restrict__ colptr) {
    __shared__ int part[256];
    __shared__ int base[257];
    int t = threadIdx.x;
    int s = 0;
    for (int i = 0; i < 64; i++) s += colcnt[t * 64 + i];
    part[t] = s;
    __syncthreads();
    if (t == 0) {
        int acc = 0;
        for (int i = 0; i < 256; i++) { base[i] = acc; acc += part[i]; }
        base[256] = acc;
    }
    __syncthreads();
    int acc = base[t];
    for (int i = 0; i < 64; i++) { int c = t * 64 + i; colptr[c] = acc; acc += colcnt[c]; }
    if (t == 255) colptr[NN] = base[256];
}

__global__ void k_fill(const int* __restrict__ vc, const int* __restrict__ colptr,
                       int* colfill, int* coledges) {
    int e = blockIdx.x * 256 + threadIdx.x;
    if (e >= MM * DEG) return;
    int c = vc[e];
    if (c < NN) {
        int p = colptr[c] + atomicAdd(&colfill[c], 1);
        coledges[p] = e;
    }
}

// deterministic: sort each column's edge list ascending (order-independent result)
__global__ void k_sort(const int* __restrict__ colptr, int* coledges) {
    int n = blockIdx.x * 256 + threadIdx.x;
    if (n >= NN) return;
    int p0 = colptr[n], p1 = colptr[n + 1];
    for (int i = p0 + 1; i < p1; i++) {
        int v = coledges[i];
        int j = i - 1;
        while (j >= p0 && coledges[j] > v) { coledges[j + 1] = coledges[j]; j--; }
        coledges[j + 1] = v;
    }
}

// ---------------- iteration kernels ----------------

// check-node update. block = m, thread handles batches (2t, 2t+1).
// No per-edge message array: writes only compact state {v0=beta*min0,
// v1=beta*min1, neg(10b), q(1b), i0(4b)}. Previous messages are reconstructed
// from the previous state (bit-exact: multiplying by +-1 is exact, and
// (d==i0) == (ab[d]==min0) because duplicate mins force min1==min0).
__global__ void k_check(const int* __restrict__ vc, const float* __restrict__ lv,
                        float* __restrict__ sv0, float* __restrict__ sv1,
                        u16* __restrict__ sbits, const u8* __restrict__ syndb,
                        float beta, int first) {
    __shared__ int cs[DEG];
    int m = blockIdx.x, t = threadIdx.x;
    if (t < DEG) cs[t] = vc[m * DEG + t];
    __syncthreads();
    int b2 = t * 2;
    size_t mb = (size_t)m * BB + b2;

    float pv0x = 0.f, pv0y = 0.f, pv1x = 0.f, pv1y = 0.f;
    unsigned pbx = 0, pby = 0;
    if (!first) {
        float2 a0 = *(const float2*)(sv0 + mb);
        float2 a1 = *(const float2*)(sv1 + mb);
        ushort2 pb = *(const ushort2*)(sbits + mb);
        pv0x = a0.x; pv0y = a0.y; pv1x = a1.x; pv1y = a1.y;
        pbx = pb.x; pby = pb.y;
    }
    int pi0x = (pbx >> 11) & 15, pi0y = (pby >> 11) & 15;
    unsigned pqx = (pbx >> 10) & 1u, pqy = (pby >> 10) & 1u;

    float m0x = INFINITY, m1x = INFINITY, m0y = INFINITY, m1y = INFINITY;
    unsigned negx = 0, negy = 0;
    int i0x = 0, i0y = 0;

    #pragma unroll
    for (int d = 0; d < DEG; d++) {
        int c = cs[d];
        float ax, ay;
        if (c >= NN) {
            ax = INFINITY; ay = INFINITY;
        } else {
            float2 g = *(const float2*)(lv + (size_t)c * BB + b2);
            if (first) { ax = g.x; ay = g.y; }
            else {
                float tx = (d == pi0x) ? pv1x : pv0x;
                float ty = (d == pi0y) ? pv1y : pv0y;
                unsigned sx = pqx ^ ((pbx >> d) & 1u);
                unsigned sy = pqy ^ ((pby >> d) & 1u);
                ax = g.x - (sx ? -tx : tx);
                ay = g.y - (sy ? -ty : ty);
            }
        }
        if (!(ax > 0.0f)) negx |= 1u << d;   // sign(a<=0) = -1 (matches ref sign(0)->-1)
        if (!(ay > 0.0f)) negy |= 1u << d;
        float xx = fabsf(ax), xy = fabsf(ay);
        if (xx < m0x) { m1x = m0x; m0x = xx; i0x = d; } else if (xx < m1x) m1x = xx;
        if (xy < m0y) { m1y = m0y; m0y = xy; i0y = d; } else if (xy < m1y) m1y = xy;
    }
    uchar2 sb = *(const uchar2*)(syndb + mb);
    unsigned qx = (__popc(negx) & 1u) ^ (sb.x ? 1u : 0u);
    unsigned qy = (__popc(negy) & 1u) ^ (sb.y ? 1u : 0u);

    *(float2*)(sv0 + mb) = make_float2(beta * m0x, beta * m0y);
    *(float2*)(sv1 + mb) = make_float2(beta * m1x, beta * m1y);
    ushort2 nb;
    nb.x = (u16)(negx | (qx << 10) | ((unsigned)i0x << 11));
    nb.y = (u16)(negy | (qy << 10) | ((unsigned)i0y << 11));
    *(ushort2*)(sbits + mb) = nb;
}

// variable-node update: block = n, thread handles batches (2t, 2t+1).
// Deterministic ascending-edge sum; messages reconstructed bit-exactly from
// the check-state planes (1KB-coalesced in b for each edge).
__global__ void k_var(const float* __restrict__ llr0t,
                      const float* __restrict__ sv0, const float* __restrict__ sv1,
                      const u16* __restrict__ sbits,
                      const int* __restrict__ colptr, const int* __restrict__ coledges,
                      float* __restrict__ lv, const int* __restrict__ niter) {
    int n = blockIdx.x, t = threadIdx.x, b2 = t * 2;
    int f0 = niter[b2], f1 = niter[b2 + 1];
    if (f0 != -1 && f1 != -1) return;
    float2 s = *(const float2*)(llr0t + (size_t)n * BB + b2);
    int p0 = colptr[n], p1 = colptr[n + 1];
    for (int p = p0; p < p1; p++) {
        int e = coledges[p];
        int m = (int)(((long long)e * 0x66666667LL) >> 34);   // e / 10 (e >= 0)
        int d = e - m * DEG;
        size_t mb = (size_t)m * BB + b2;
        float2 v0 = *(const float2*)(sv0 + mb);
        float2 v1 = *(const float2*)(sv1 + mb);
        ushort2 bb = *(const ushort2*)(sbits + mb);
        float tx = (d == ((bb.x >> 11) & 15)) ? v1.x : v0.x;
        float ty = (d == ((bb.y >> 11) & 15)) ? v1.y : v0.y;
        unsigned sx = ((bb.x >> 10) ^ (bb.x >> d)) & 1u;
        unsigned sy = ((bb.y >> 10) ^ (bb.y >> d)) & 1u;
        s.x += sx ? -tx : tx;
        s.y += sy ? -ty : ty;
    }
    float* dst = lv + (size_t)n * BB + b2;
    if (f0 == -1 && f1 == -1) *(float2*)dst = s;
    else if (f0 == -1) dst[0] = s.x;
    else dst[1] = s.y;
}

// persistent grid-strided parity (reads lv signs) with block-level early exit,
// convergence finalization folded into the last-finishing block (ticket).
// mm[b] is set-only within an iteration -> deterministic final state.
__global__ void k_parity(const int* __restrict__ vc, const float* __restrict__ lv,
                         const u8* __restrict__ syndb, int* __restrict__ niter,
                         int* __restrict__ conv, int* __restrict__ mm,
                         int* __restrict__ cnt, int it) {
    __shared__ int s_stop, s_last;
    int b = threadIdx.x;
    bool frozen = (niter[b] != -1);
    volatile int* vmm = (volatile int*)mm;

    for (int m = blockIdx.x; m < MM; m += PAR_BLOCKS) {
        if (b == 0) s_stop = 1;
        __syncthreads();
        bool flagged = frozen || (vmm[b] != 0);
        if (!flagged) s_stop = 0;
        __syncthreads();
        if (s_stop) break;
        if (!flagged) {
            unsigned par = 0;
            #pragma unroll
            for (int d = 0; d < DEG; d++) {
                int c = vc[m * DEG + d];
                if (c < NN) par ^= (lv[(size_t)c * BB + b] <= 0.0f) ? 1u : 0u;
            }
            if (par != (unsigned)syndb[(size_t)m * BB + b]) atomicOr(&mm[b], 1);
        }
    }
    __syncthreads();
    __threadfence();
    if (b == 0) {
        int tk = atomicAdd(cnt, 1);
        s_last = (tk == PAR_BLOCKS - 1) ? 1 : 0;
    }
    __syncthreads();
    if (s_last) {
        __threadfence();
        if (niter[b] == -1 && mm[b] == 0) { niter[b] = it; conv[b] = 1; }
        mm[b] = 0;
        if (b == 0) *cnt = 0;
    }
}

// ---------------- epilogue ----------------

__global__ void k_out_e(const float* __restrict__ lv, float* __restrict__ out) {
    __shared__ float tile[64][65];
    int c0 = blockIdx.x * 64;   // b
    int r0 = blockIdx.y * 64;   // n
    #pragma unroll
    for (int k = 0; k < 16; k++) {
        int idx = k * 256 + threadIdx.x;
        int i = idx >> 6, j = idx & 63;
        tile[i][j] = (lv[(size_t)(r0 + i) * BB + (c0 + j)] <= 0.0f) ? 1.0f : 0.0f;
    }
    __syncthreads();
    #pragma unroll
    for (int k = 0; k < 16; k++) {
        int idx = k * 256 + threadIdx.x;
        int i = idx >> 6, j = idx & 63;
        out[(size_t)(c0 + i) * NN + (r0 + j)] = tile[j][i];
    }
}

__global__ void k_out_scalars(const int* __restrict__ niter, const int* __restrict__ conv,
                              float* __restrict__ out_ni, float* __restrict__ out_conv) {
    int b = threadIdx.x;
    int ni = niter[b];
    out_ni[b] = (float)(ni == -1 ? MAX_ITER : ni);
    out_conv[b] = (float)conv[b];
}

// ---------------- launch ----------------

extern "C" void kernel_launch(void* const* d_in, const int* in_sizes, int n_in,
                              void* d_out, int out_size, void* d_ws, size_t ws_size,
                              hipStream_t stream) {
    const float* synd = (const float*)d_in[0];   // (B, M)
    const float* llr0 = (const float*)d_in[1];   // (B, N)
    const int* vcol   = (const int*)d_in[3];     // (M, DEG)
    float* out = (float*)d_out;

    char* ws = (char*)d_ws;
    size_t off = 0;
    auto alloc = [&](size_t bytes) {
        off = (off + 255) & ~(size_t)255;
        size_t o = off; off += bytes; return o;
    };
    float* llr0t  = (float*)(ws + alloc((size_t)NN * BB * 4));
    float* lv     = (float*)(ws + alloc((size_t)NN * BB * 4));
    float* sv0    = (float*)(ws + alloc((size_t)MM * BB * 4));
    float* sv1    = (float*)(ws + alloc((size_t)MM * BB * 4));
    u16*   sbits  = (u16*)(ws + alloc((size_t)MM * BB * 2));
    u8*   syndb   = (u8*)(ws + alloc((size_t)MM * BB));
    int* coledges = (int*)(ws + alloc((size_t)MM * DEG * 4));
    int* colptr   = (int*)(ws + alloc((size_t)(NN + 1) * 4));
    int* colcnt   = (int*)(ws + alloc((size_t)NN * 4));
    int* colfill  = (int*)(ws + alloc((size_t)NN * 4));
    int* mm       = (int*)(ws + alloc((size_t)BB * 4));
    int* niter    = (int*)(ws + alloc((size_t)BB * 4));
    int* conv     = (int*)(ws + alloc((size_t)BB * 4));
    int* cnt      = (int*)(ws + alloc(256));
    (void)in_sizes; (void)n_in; (void)out_size; (void)ws_size;

    // prologue
    k_init<<<NN / 256, 256, 0, stream>>>(colcnt, colfill, mm, niter, conv, cnt);
    k_transpose_f32<<<dim3(NN / 64, BB / 64), 256, 0, stream>>>(llr0, llr0t, lv, BB, NN);
    k_synd_t<<<dim3(MM / 64, BB / 64), 256, 0, stream>>>(synd, syndb);
    k_hist<<<(MM * DEG + 255) / 256, 256, 0, stream>>>(vcol, colcnt);
    k_scan<<<1, 256, 0, stream>>>(colcnt, colptr);
    k_fill<<<(MM * DEG + 255) / 256, 256, 0, stream>>>(vcol, colptr, colfill, coledges);
    k_sort<<<NN / 256, 256, 0, stream>>>(colptr, coledges);

    // main loop
    for (int i = 1; i <= MAX_ITER; i++) {
        float beta = 1.0f - ldexpf(1.0f, -i);
        k_check<<<MM, 128, 0, stream>>>(vcol, lv, sv0, sv1, sbits, syndb,
                                        beta, (i == 1) ? 1 : 0);
        k_var<<<NN, 128, 0, stream>>>(llr0t, sv0, sv1, sbits, colptr, coledges, lv, niter);
        k_parity<<<PAR_BLOCKS, 256, 0, stream>>>(vcol, lv, syndb, niter, conv, mm, cnt, i);
    }

    // epilogue: e_out | num_iters | l_out | conv
    size_t off_e = 0;
    size_t off_ni = (size_t)BB * NN;
    size_t off_l = off_ni + BB;
    size_t off_c = off_l + (size_t)BB * NN;
    k_out_e<<<dim3(BB / 64, NN / 64), 256, 0, stream>>>(lv, out + off_e);
    k_transpose_f32<<<dim3(BB / 64, NN / 64), 256, 0, stream>>>(lv, out + off_l, nullptr, NN, BB);
    k_out_scalars<<<1, 256, 0, stream>>>(niter, conv, out + off_ni, out + off_c);
}